// Round 1
// baseline (170.093 us; speedup 1.0000x reference)
//
#include <hip/hip_runtime.h>

// MultiHeadSelfAttention: N=8, C=512, heads=8, d=64, S=1024 (32x32), fp32 in/out.
// Strategy: fp16 MFMA compute (fp32 accum), exp2-domain online softmax,
// NT GEMMs with global_load_lds staging, XOR-swizzled LDS to kill bank conflicts.

typedef _Float16 f16x8 __attribute__((ext_vector_type(8)));
typedef float f32x4 __attribute__((ext_vector_type(4)));

__device__ inline void gl_lds16(const void* g, void* l) {
  __builtin_amdgcn_global_load_lds((const __attribute__((address_space(1))) void*)g,
                                   (__attribute__((address_space(3))) void*)l, 16, 0, 0);
}

__device__ inline float fexp2(float x) {
#if __has_builtin(__builtin_amdgcn_exp2f)
  return __builtin_amdgcn_exp2f(x);
#else
  return exp2f(x);
#endif
}

// ---------------- prep: transpose+cast x (N,C,S)->(N,S,C) fp16 ----------------
__global__ void prep_x(const float* __restrict__ x, _Float16* __restrict__ xs16) {
  __shared__ float t[32][33];
  const int n = blockIdx.z;
  const int s0 = blockIdx.x * 32, c0 = blockIdx.y * 32;
  const int tx = threadIdx.x, ty = threadIdx.y;
#pragma unroll
  for (int i = 0; i < 4; ++i) {
    int cc = ty + i * 8;
    t[cc][tx] = x[((size_t)n * 512 + c0 + cc) * 1024 + s0 + tx];
  }
  __syncthreads();
#pragma unroll
  for (int i = 0; i < 4; ++i) {
    int ss = ty + i * 8;
    xs16[((size_t)n * 1024 + s0 + ss) * 512 + c0 + tx] = (_Float16)t[tx][ss];
  }
}

// ---------------- prep: weights -> fp16, fold (1/8)*log2(e) into Wq,bq --------
__global__ void prep_w(const float* __restrict__ Wq, const float* __restrict__ bq,
                       const float* __restrict__ Wk, const float* __restrict__ bk,
                       const float* __restrict__ Wv, const float* __restrict__ bv,
                       const float* __restrict__ Wo,
                       _Float16* __restrict__ Wqkv16, float* __restrict__ bqkv,
                       _Float16* __restrict__ Wo16) {
  const float g = 0.18033688011112042f;  // log2(e)/8
  int i = blockIdx.x * 256 + threadIdx.x;  // 0..262143
  Wqkv16[i]          = (_Float16)(Wq[i] * g);
  Wqkv16[262144 + i] = (_Float16)Wk[i];
  Wqkv16[524288 + i] = (_Float16)Wv[i];
  Wo16[i]            = (_Float16)Wo[i];
  if (i < 512) {
    bqkv[i]        = bq[i] * g;
    bqkv[512 + i]  = bk[i];
    bqkv[1024 + i] = bv[i];
  }
}

// ---------------- QKV GEMM: (8192x512)*(1536x512)^T + bias -------------------
// Q,K -> QK[m][0..1023] fp16 ; V -> Vt[(n*8+h)][d][s] fp16 (pre-transposed)
__global__ __launch_bounds__(256, 2) void qkv_gemm(
    const _Float16* __restrict__ A, const _Float16* __restrict__ Bw,
    const float* __restrict__ bias, _Float16* __restrict__ QK,
    _Float16* __restrict__ Vt) {
  __shared__ _Float16 As[128 * 32];
  __shared__ _Float16 Bs[128 * 32];
  const int tid = threadIdx.x;
  const int lane = tid & 63, w = tid >> 6;
  const int quad = lane >> 4, l15 = lane & 15;
  const int bm = blockIdx.x * 128, bn = blockIdx.y * 128;
  const int wr = (w >> 1) * 64, wc = (w & 1) * 64;
  f32x4 acc[4][4] = {};
  for (int k0 = 0; k0 < 512; k0 += 32) {
    __syncthreads();
#pragma unroll
    for (int c = 0; c < 2; ++c) {
      int idx = c * 256 + tid;
      int row = idx >> 2, sc = idx & 3;
      int kg = sc ^ ((row >> 1) & 3);  // XOR swizzle: global chunk for this slot
      gl_lds16(A + (size_t)(bm + row) * 512 + k0 + kg * 8, As + idx * 8);
      gl_lds16(Bw + (size_t)(bn + row) * 512 + k0 + kg * 8, Bs + idx * 8);
    }
    __syncthreads();
    f16x8 af[4], bf[4];
#pragma unroll
    for (int i = 0; i < 4; ++i) {
      int ra = wr + i * 16 + l15;
      af[i] = *(const f16x8*)(As + ra * 32 + (quad ^ ((ra >> 1) & 3)) * 8);
      int rb = wc + i * 16 + l15;
      bf[i] = *(const f16x8*)(Bs + rb * 32 + (quad ^ ((rb >> 1) & 3)) * 8);
    }
#pragma unroll
    for (int i = 0; i < 4; ++i)
#pragma unroll
      for (int j = 0; j < 4; ++j)
        acc[i][j] = __builtin_amdgcn_mfma_f32_16x16x32_f16(af[i], bf[j], acc[i][j], 0, 0, 0);
  }
#pragma unroll
  for (int j = 0; j < 4; ++j) {
    int col = bn + wc + j * 16 + l15;
    float bb = bias[col];
#pragma unroll
    for (int i = 0; i < 4; ++i) {
      int rowb = bm + wr + i * 16 + quad * 4;
#pragma unroll
      for (int r = 0; r < 4; ++r) {
        int m = rowb + r;
        _Float16 hv = (_Float16)(acc[i][j][r] + bb);
        if (col < 1024) {
          QK[(size_t)m * 1024 + col] = hv;
        } else {
          int n = m >> 10, s = m & 1023;
          int hh = (col - 1024) >> 6, d = (col - 1024) & 63;
          Vt[(((size_t)((n * 8 + hh) * 64 + d)) << 10) + s] = hv;
        }
      }
    }
  }
}

// ---------------- flash attention: one block per (qtile of 128, n*8+h) --------
__global__ __launch_bounds__(256, 2) void attn(
    const _Float16* __restrict__ QK, const _Float16* __restrict__ Vt,
    _Float16* __restrict__ O16) {
  __shared__ _Float16 Ks[128 * 64];   // [s][d], swizzled
  __shared__ _Float16 Vs[64 * 128];   // [d][s], swizzled
  __shared__ _Float16 U[16384];       // Qs [128][64] first, then Ps[w][32][128]
  const int tid = threadIdx.x, lane = tid & 63, w = tid >> 6;
  const int quad = lane >> 4, l15 = lane & 15;
  const int n = blockIdx.y >> 3, h = blockIdx.y & 7;
  const int q0 = blockIdx.x * 128;
  // stage Q (once)
#pragma unroll
  for (int c = 0; c < 4; ++c) {
    int idx = c * 256 + tid;
    int row = idx >> 3, sc = idx & 7;
    int dg = sc ^ (row & 7);
    gl_lds16(QK + (size_t)(n * 1024 + q0 + row) * 1024 + h * 64 + dg * 8, U + idx * 8);
  }
  __syncthreads();
  f16x8 qf[2][2];
#pragma unroll
  for (int mt = 0; mt < 2; ++mt)
#pragma unroll
    for (int kc = 0; kc < 2; ++kc) {
      int row = w * 32 + mt * 16 + l15;
      qf[mt][kc] = *(const f16x8*)(U + row * 64 + ((kc * 4 + quad) ^ (row & 7)) * 8);
    }
  float mrun[2][4], lrun[2][4];
  f32x4 oacc[2][4] = {};
#pragma unroll
  for (int mt = 0; mt < 2; ++mt)
#pragma unroll
    for (int r = 0; r < 4; ++r) { mrun[mt][r] = -1e30f; lrun[mt][r] = 0.f; }
  _Float16* Pw = U + w * 4096;  // wave-private 32x128

  for (int kt = 0; kt < 8; ++kt) {
    __syncthreads();
#pragma unroll
    for (int c = 0; c < 4; ++c) {
      int idx = c * 256 + tid;
      int row = idx >> 3, sck = idx & 7;
      int dg = sck ^ (row & 7);
      gl_lds16(QK + (size_t)(n * 1024 + kt * 128 + row) * 1024 + 512 + h * 64 + dg * 8,
               Ks + idx * 8);
      int d = idx >> 4, scv = idx & 15;
      int sg = scv ^ (d & 7);
      gl_lds16(Vt + (size_t)((n * 8 + h) * 64 + d) * 1024 + kt * 128 + sg * 8,
               Vs + idx * 8);
    }
    __syncthreads();
    // S = Q * K^T  (scale already folded into Q)
    f32x4 sacc[2][8] = {};
#pragma unroll
    for (int ct = 0; ct < 8; ++ct) {
      int rk = ct * 16 + l15;
      f16x8 kf0 = *(const f16x8*)(Ks + rk * 64 + ((quad) ^ (rk & 7)) * 8);
      f16x8 kf1 = *(const f16x8*)(Ks + rk * 64 + ((4 + quad) ^ (rk & 7)) * 8);
#pragma unroll
      for (int mt = 0; mt < 2; ++mt) {
        sacc[mt][ct] = __builtin_amdgcn_mfma_f32_16x16x32_f16(qf[mt][0], kf0, sacc[mt][ct], 0, 0, 0);
        sacc[mt][ct] = __builtin_amdgcn_mfma_f32_16x16x32_f16(qf[mt][1], kf1, sacc[mt][ct], 0, 0, 0);
      }
    }
    // online softmax in exp2 domain; rows = quad*4+r (+16*mt), cols across l15/ct
#pragma unroll
    for (int mt = 0; mt < 2; ++mt) {
#pragma unroll
      for (int r = 0; r < 4; ++r) {
        float rmax = sacc[mt][0][r];
#pragma unroll
        for (int ct = 1; ct < 8; ++ct) rmax = fmaxf(rmax, sacc[mt][ct][r]);
#pragma unroll
        for (int msk = 1; msk < 16; msk <<= 1) rmax = fmaxf(rmax, __shfl_xor(rmax, msk, 64));
        float mnew = fmaxf(mrun[mt][r], rmax);
        float alpha = fexp2(mrun[mt][r] - mnew);
        mrun[mt][r] = mnew;
        float rsum = 0.f;
#pragma unroll
        for (int ct = 0; ct < 8; ++ct) {
          float p = fexp2(sacc[mt][ct][r] - mnew);
          sacc[mt][ct][r] = p;
          rsum += p;
        }
#pragma unroll
        for (int msk = 1; msk < 16; msk <<= 1) rsum += __shfl_xor(rsum, msk, 64);
        lrun[mt][r] = lrun[mt][r] * alpha + rsum;
#pragma unroll
        for (int nt = 0; nt < 4; ++nt) oacc[mt][nt][r] *= alpha;
        int prow = mt * 16 + quad * 4 + r;
#pragma unroll
        for (int ct = 0; ct < 8; ++ct) {
          int col = ct * 16 + l15;
          Pw[prow * 128 + ((col >> 3) ^ (prow & 7)) * 8 + (col & 7)] =
              (_Float16)sacc[mt][ct][r];
        }
      }
    }
    // O += P * V
#pragma unroll
    for (int kc = 0; kc < 4; ++kc) {
      f16x8 pf[2], vf[4];
#pragma unroll
      for (int mt = 0; mt < 2; ++mt) {
        int m = mt * 16 + l15;
        pf[mt] = *(const f16x8*)(Pw + m * 128 + ((kc * 4 + quad) ^ (m & 7)) * 8);
      }
#pragma unroll
      for (int nt = 0; nt < 4; ++nt) {
        int d = nt * 16 + l15;
        vf[nt] = *(const f16x8*)(Vs + d * 128 + ((kc * 4 + quad) ^ (d & 7)) * 8);
      }
#pragma unroll
      for (int mt = 0; mt < 2; ++mt)
#pragma unroll
        for (int nt = 0; nt < 4; ++nt)
          oacc[mt][nt] = __builtin_amdgcn_mfma_f32_16x16x32_f16(pf[mt], vf[nt], oacc[mt][nt], 0, 0, 0);
    }
  }
  // epilogue: divide by l, store with torch-reshape permutation:
  // (n,h,s,d) -> row i = h*128 + s/8, col j = (s%8)*64 + d
#pragma unroll
  for (int mt = 0; mt < 2; ++mt) {
#pragma unroll
    for (int r = 0; r < 4; ++r) {
      float rinv = 1.0f / lrun[mt][r];
      int s = q0 + w * 32 + mt * 16 + quad * 4 + r;
      int i = h * 128 + (s >> 3);
      int jb = (s & 7) * 64;
#pragma unroll
      for (int nt = 0; nt < 4; ++nt) {
        int d = nt * 16 + l15;
        O16[(size_t)(n * 1024 + i) * 512 + jb + d] = (_Float16)(oacc[mt][nt][r] * rinv);
      }
    }
  }
}

// ---------------- out GEMM: (8192x512)*(512x512)^T + bo -> fp32 out ----------
__global__ __launch_bounds__(256, 2) void out_gemm(
    const _Float16* __restrict__ A, const _Float16* __restrict__ Bw,
    const float* __restrict__ bias, float* __restrict__ out) {
  __shared__ _Float16 As[128 * 32];
  __shared__ _Float16 Bs[128 * 32];
  const int tid = threadIdx.x;
  const int lane = tid & 63, w = tid >> 6;
  const int quad = lane >> 4, l15 = lane & 15;
  const int bm = blockIdx.x * 128, bn = blockIdx.y * 128;
  const int wr = (w >> 1) * 64, wc = (w & 1) * 64;
  f32x4 acc[4][4] = {};
  for (int k0 = 0; k0 < 512; k0 += 32) {
    __syncthreads();
#pragma unroll
    for (int c = 0; c < 2; ++c) {
      int idx = c * 256 + tid;
      int row = idx >> 2, sc = idx & 3;
      int kg = sc ^ ((row >> 1) & 3);
      gl_lds16(A + (size_t)(bm + row) * 512 + k0 + kg * 8, As + idx * 8);
      gl_lds16(Bw + (size_t)(bn + row) * 512 + k0 + kg * 8, Bs + idx * 8);
    }
    __syncthreads();
    f16x8 af[4], bf[4];
#pragma unroll
    for (int i = 0; i < 4; ++i) {
      int ra = wr + i * 16 + l15;
      af[i] = *(const f16x8*)(As + ra * 32 + (quad ^ ((ra >> 1) & 3)) * 8);
      int rb = wc + i * 16 + l15;
      bf[i] = *(const f16x8*)(Bs + rb * 32 + (quad ^ ((rb >> 1) & 3)) * 8);
    }
#pragma unroll
    for (int i = 0; i < 4; ++i)
#pragma unroll
      for (int j = 0; j < 4; ++j)
        acc[i][j] = __builtin_amdgcn_mfma_f32_16x16x32_f16(af[i], bf[j], acc[i][j], 0, 0, 0);
  }
#pragma unroll
  for (int j = 0; j < 4; ++j) {
    int col = bn + wc + j * 16 + l15;
    float bb = bias[col];
#pragma unroll
    for (int i = 0; i < 4; ++i) {
      int rowb = bm + wr + i * 16 + quad * 4;
#pragma unroll
      for (int r = 0; r < 4; ++r)
        out[(size_t)(rowb + r) * 512 + col] = acc[i][j][r] + bb;
    }
  }
}

extern "C" void kernel_launch(void* const* d_in, const int* in_sizes, int n_in,
                              void* d_out, int out_size, void* d_ws, size_t ws_size,
                              hipStream_t stream) {
  const float* x  = (const float*)d_in[0];
  const float* Wq = (const float*)d_in[1];
  const float* bq = (const float*)d_in[2];
  const float* Wk = (const float*)d_in[3];
  const float* bk = (const float*)d_in[4];
  const float* Wv = (const float*)d_in[5];
  const float* bv = (const float*)d_in[6];
  const float* Wo = (const float*)d_in[7];
  const float* bo = (const float*)d_in[8];
  float* out = (float*)d_out;
  char* ws = (char*)d_ws;

  _Float16* xs16   = (_Float16*)(ws);                          // 8 MB (reused as O16)
  _Float16* QK     = (_Float16*)(ws + (8u << 20));             // 16 MB
  _Float16* Vt     = (_Float16*)(ws + (24u << 20));            // 8 MB
  _Float16* Wqkv16 = (_Float16*)(ws + (32u << 20));            // 1.5 MB
  _Float16* Wo16   = (_Float16*)(ws + (32u << 20) + 1572864);  // 0.5 MB
  float*    bqkv   = (float*)   (ws + (32u << 20) + 2097152);  // 6 KB

  hipLaunchKernelGGL(prep_x, dim3(32, 16, 8), dim3(32, 8), 0, stream, x, xs16);
  hipLaunchKernelGGL(prep_w, dim3(1024), dim3(256), 0, stream,
                     Wq, bq, Wk, bk, Wv, bv, Wo, Wqkv16, bqkv, Wo16);
  hipLaunchKernelGGL(qkv_gemm, dim3(64, 12), dim3(256), 0, stream,
                     xs16, Wqkv16, bqkv, QK, Vt);
  hipLaunchKernelGGL(attn, dim3(8, 64), dim3(256), 0, stream, QK, Vt, xs16);
  hipLaunchKernelGGL(out_gemm, dim3(64, 4), dim3(256), 0, stream,
                     xs16, Wo16, bo, out);
}

// Round 2
// 160.675 us; speedup vs baseline: 1.0586x; 1.0586x over previous
//
#include <hip/hip_runtime.h>

// MultiHeadSelfAttention: N=8, C=512, heads=8, d=64, S=1024 (32x32), fp32 in/out.
// R2: attn rewritten — S^T=K·Q^T orientation so P's C-layout IS the PV A-layout
// (with an s-permutation folded into Vt storage); no-max exp2 softmax; l via
// ones-column MFMA; P never touches LDS. 64 q-rows/wave halves LDS read volume.

typedef _Float16 f16x8 __attribute__((ext_vector_type(8)));
typedef float f32x4 __attribute__((ext_vector_type(4)));

__device__ inline void gl_lds16(const void* g, void* l) {
  __builtin_amdgcn_global_load_lds((const __attribute__((address_space(1))) void*)g,
                                   (__attribute__((address_space(3))) void*)l, 16, 0, 0);
}

__device__ inline float fexp2(float x) {
#if __has_builtin(__builtin_amdgcn_exp2f)
  return __builtin_amdgcn_exp2f(x);
#else
  return exp2f(x);
#endif
}

// ---------------- prep: transpose+cast x (N,C,S)->(N,S,C) fp16 ----------------
__global__ void prep_x(const float* __restrict__ x, _Float16* __restrict__ xs16) {
  __shared__ float t[32][33];
  const int n = blockIdx.z;
  const int s0 = blockIdx.x * 32, c0 = blockIdx.y * 32;
  const int tx = threadIdx.x, ty = threadIdx.y;
#pragma unroll
  for (int i = 0; i < 4; ++i) {
    int cc = ty + i * 8;
    t[cc][tx] = x[((size_t)n * 512 + c0 + cc) * 1024 + s0 + tx];
  }
  __syncthreads();
#pragma unroll
  for (int i = 0; i < 4; ++i) {
    int ss = ty + i * 8;
    xs16[((size_t)n * 1024 + s0 + ss) * 512 + c0 + tx] = (_Float16)t[tx][ss];
  }
}

// ---------------- prep: weights -> fp16, fold (1/8)*log2(e) into Wq,bq --------
__global__ void prep_w(const float* __restrict__ Wq, const float* __restrict__ bq,
                       const float* __restrict__ Wk, const float* __restrict__ bk,
                       const float* __restrict__ Wv, const float* __restrict__ bv,
                       const float* __restrict__ Wo,
                       _Float16* __restrict__ Wqkv16, float* __restrict__ bqkv,
                       _Float16* __restrict__ Wo16) {
  const float g = 0.18033688011112042f;  // log2(e)/8
  int i = blockIdx.x * 256 + threadIdx.x;  // 0..262143
  Wqkv16[i]          = (_Float16)(Wq[i] * g);
  Wqkv16[262144 + i] = (_Float16)Wk[i];
  Wqkv16[524288 + i] = (_Float16)Wv[i];
  Wo16[i]            = (_Float16)Wo[i];
  if (i < 512) {
    bqkv[i]        = bq[i] * g;
    bqkv[512 + i]  = bk[i];
    bqkv[1024 + i] = bv[i];
  }
}

// ---------------- QKV GEMM: (8192x512)*(1536x512)^T + bias -------------------
// Q,K -> QK[m][0..1023] fp16 ; V -> Vt[(n*8+h)][d][p] fp16, s-permuted so that
// within each 32-block, position p = q*8 + t*4 + r holds s_local = 16t + 4q + r
// (matches the PV MFMA k-index mapping used in attn).
__global__ __launch_bounds__(256, 2) void qkv_gemm(
    const _Float16* __restrict__ A, const _Float16* __restrict__ Bw,
    const float* __restrict__ bias, _Float16* __restrict__ QK,
    _Float16* __restrict__ Vt) {
  __shared__ _Float16 As[128 * 32];
  __shared__ _Float16 Bs[128 * 32];
  const int tid = threadIdx.x;
  const int lane = tid & 63, w = tid >> 6;
  const int quad = lane >> 4, l15 = lane & 15;
  const int bm = blockIdx.x * 128, bn = blockIdx.y * 128;
  const int wr = (w >> 1) * 64, wc = (w & 1) * 64;
  f32x4 acc[4][4] = {};
  for (int k0 = 0; k0 < 512; k0 += 32) {
    __syncthreads();
#pragma unroll
    for (int c = 0; c < 2; ++c) {
      int idx = c * 256 + tid;
      int row = idx >> 2, sc = idx & 3;
      int kg = sc ^ ((row >> 1) & 3);
      gl_lds16(A + (size_t)(bm + row) * 512 + k0 + kg * 8, As + idx * 8);
      gl_lds16(Bw + (size_t)(bn + row) * 512 + k0 + kg * 8, Bs + idx * 8);
    }
    __syncthreads();
    f16x8 af[4], bf[4];
#pragma unroll
    for (int i = 0; i < 4; ++i) {
      int ra = wr + i * 16 + l15;
      af[i] = *(const f16x8*)(As + ra * 32 + (quad ^ ((ra >> 1) & 3)) * 8);
      int rb = wc + i * 16 + l15;
      bf[i] = *(const f16x8*)(Bs + rb * 32 + (quad ^ ((rb >> 1) & 3)) * 8);
    }
#pragma unroll
    for (int i = 0; i < 4; ++i)
#pragma unroll
      for (int j = 0; j < 4; ++j)
        acc[i][j] = __builtin_amdgcn_mfma_f32_16x16x32_f16(af[i], bf[j], acc[i][j], 0, 0, 0);
  }
#pragma unroll
  for (int j = 0; j < 4; ++j) {
    int col = bn + wc + j * 16 + l15;
    float bb = bias[col];
#pragma unroll
    for (int i = 0; i < 4; ++i) {
      int rowb = bm + wr + i * 16 + quad * 4;
#pragma unroll
      for (int r = 0; r < 4; ++r) {
        int m = rowb + r;
        _Float16 hv = (_Float16)(acc[i][j][r] + bb);
        if (col < 1024) {
          QK[(size_t)m * 1024 + col] = hv;
        } else {
          int n = m >> 10, s = m & 1023;
          int hh = (col - 1024) >> 6, d = (col - 1024) & 63;
          int sl = s & 31;
          int p = (s & ~31) | (((sl >> 2) & 3) << 3) | ((sl >> 4) << 2) | (sl & 3);
          Vt[(((size_t)((n * 8 + hh) * 64 + d)) << 10) + p] = hv;
        }
      }
    }
  }
}

// ---------------- flash attention v2 ------------------------------------------
// Block: 128 threads (2 waves), covers 128 q-rows; wave handles 64 rows (mt=0..3).
// Grid: (8 q-tiles, 64 n*h). LDS: Qs 16K + Ks 16K + Vs 16K = 48 KB.
__global__ __launch_bounds__(128, 1) void attn(
    const _Float16* __restrict__ QK, const _Float16* __restrict__ Vt,
    _Float16* __restrict__ O16) {
  __shared__ _Float16 Qs[128 * 64];
  __shared__ _Float16 Ks[128 * 64];
  __shared__ _Float16 Vs[64 * 128];
  const int tid = threadIdx.x, lane = tid & 63, w = tid >> 6;
  const int quad = lane >> 4, l15 = lane & 15;
  const int n = blockIdx.y >> 3, h = blockIdx.y & 7;
  const int q0 = blockIdx.x * 128;
  // stage Q once: slot (row, sc) holds global d-chunk sc^(row&7)
#pragma unroll
  for (int c = 0; c < 8; ++c) {
    int idx = c * 128 + tid;
    int row = idx >> 3, sc = idx & 7;
    int dg = sc ^ (row & 7);
    gl_lds16(QK + (size_t)(n * 1024 + q0 + row) * 1024 + h * 64 + dg * 8, Qs + idx * 8);
  }
  __syncthreads();
  // Q fragments (B-operand of S^T): lane l15 = q-row, quad = d-subchunk
  f16x8 qf[4][2];
#pragma unroll
  for (int mt = 0; mt < 4; ++mt)
#pragma unroll
    for (int dc = 0; dc < 2; ++dc) {
      int row = w * 64 + mt * 16 + l15;
      qf[mt][dc] = *(const f16x8*)(Qs + row * 64 + ((dc * 4 + quad) ^ (row & 7)) * 8);
    }
  f32x4 oacc[4][4] = {};
  f32x4 lsum[4] = {};
  const f16x8 ones = {(_Float16)1, (_Float16)1, (_Float16)1, (_Float16)1,
                      (_Float16)1, (_Float16)1, (_Float16)1, (_Float16)1};

  for (int kt = 0; kt < 8; ++kt) {
    __syncthreads();
#pragma unroll
    for (int c = 0; c < 8; ++c) {
      int idx = c * 128 + tid;
      int row = idx >> 3, sck = idx & 7;
      int dg = sck ^ (row & 7);
      gl_lds16(QK + (size_t)(n * 1024 + kt * 128 + row) * 1024 + 512 + h * 64 + dg * 8,
               Ks + idx * 8);
      int d = idx >> 4, scv = idx & 15;
      int vg = scv ^ (d & 7);
      gl_lds16(Vt + (size_t)((n * 8 + h) * 64 + d) * 1024 + kt * 128 + vg * 8,
               Vs + idx * 8);
    }
    __syncthreads();
#pragma unroll
    for (int sc = 0; sc < 4; ++sc) {
      // S^T = K·Q^T for this 32-s chunk (2 tiles of 16)
      f32x4 sacc[4][2] = {};
#pragma unroll
      for (int t = 0; t < 2; ++t) {
        int rk = (sc * 2 + t) * 16 + l15;
        f16x8 kf0 = *(const f16x8*)(Ks + rk * 64 + ((quad) ^ (rk & 7)) * 8);
        f16x8 kf1 = *(const f16x8*)(Ks + rk * 64 + ((4 + quad) ^ (rk & 7)) * 8);
#pragma unroll
        for (int mt = 0; mt < 4; ++mt) {
          sacc[mt][t] = __builtin_amdgcn_mfma_f32_16x16x32_f16(kf0, qf[mt][0], sacc[mt][t], 0, 0, 0);
          sacc[mt][t] = __builtin_amdgcn_mfma_f32_16x16x32_f16(kf1, qf[mt][1], sacc[mt][t], 0, 0, 0);
        }
      }
      // P = exp2(S') in registers; C-layout == PV A-layout under the s-permutation
      f16x8 pf[4];
#pragma unroll
      for (int mt = 0; mt < 4; ++mt) {
#pragma unroll
        for (int t = 0; t < 2; ++t)
#pragma unroll
          for (int r = 0; r < 4; ++r)
            pf[mt][t * 4 + r] = (_Float16)fexp2(sacc[mt][t][r]);
        lsum[mt] = __builtin_amdgcn_mfma_f32_16x16x32_f16(pf[mt], ones, lsum[mt], 0, 0, 0);
      }
      // O += P·V  (B-operand: Vs rows, s-permuted storage matches k mapping)
#pragma unroll
      for (int nt = 0; nt < 4; ++nt) {
        int rd = nt * 16 + l15;
        f16x8 vf = *(const f16x8*)(Vs + rd * 128 + ((sc * 4 + quad) ^ (rd & 7)) * 8);
#pragma unroll
        for (int mt = 0; mt < 4; ++mt)
          oacc[mt][nt] = __builtin_amdgcn_mfma_f32_16x16x32_f16(pf[mt], vf, oacc[mt][nt], 0, 0, 0);
      }
    }
  }
  // epilogue: O row m: lane(quad,l15) reg r -> m=quad*4+r(+16mt), d=nt*16+l15.
  // 1/l lives in the same lane/reg (ones-column C-layout). torch-reshape store:
  // (n,h,s,d) -> row i = h*128 + s/8, col j = (s%8)*64 + d
#pragma unroll
  for (int mt = 0; mt < 4; ++mt) {
#pragma unroll
    for (int r = 0; r < 4; ++r) {
      float rinv = 1.0f / lsum[mt][r];
      int s = q0 + w * 64 + mt * 16 + quad * 4 + r;
      int i = h * 128 + (s >> 3);
      int jb = (s & 7) * 64;
#pragma unroll
      for (int nt = 0; nt < 4; ++nt) {
        int d = nt * 16 + l15;
        O16[(size_t)(n * 1024 + i) * 512 + jb + d] = (_Float16)(oacc[mt][nt][r] * rinv);
      }
    }
  }
}

// ---------------- out GEMM: (8192x512)*(512x512)^T + bo -> fp32 out ----------
__global__ __launch_bounds__(256, 2) void out_gemm(
    const _Float16* __restrict__ A, const _Float16* __restrict__ Bw,
    const float* __restrict__ bias, float* __restrict__ out) {
  __shared__ _Float16 As[128 * 32];
  __shared__ _Float16 Bs[128 * 32];
  const int tid = threadIdx.x;
  const int lane = tid & 63, w = tid >> 6;
  const int quad = lane >> 4, l15 = lane & 15;
  const int bm = blockIdx.x * 128, bn = blockIdx.y * 128;
  const int wr = (w >> 1) * 64, wc = (w & 1) * 64;
  f32x4 acc[4][4] = {};
  for (int k0 = 0; k0 < 512; k0 += 32) {
    __syncthreads();
#pragma unroll
    for (int c = 0; c < 2; ++c) {
      int idx = c * 256 + tid;
      int row = idx >> 2, sc = idx & 3;
      int kg = sc ^ ((row >> 1) & 3);
      gl_lds16(A + (size_t)(bm + row) * 512 + k0 + kg * 8, As + idx * 8);
      gl_lds16(Bw + (size_t)(bn + row) * 512 + k0 + kg * 8, Bs + idx * 8);
    }
    __syncthreads();
    f16x8 af[4], bf[4];
#pragma unroll
    for (int i = 0; i < 4; ++i) {
      int ra = wr + i * 16 + l15;
      af[i] = *(const f16x8*)(As + ra * 32 + (quad ^ ((ra >> 1) & 3)) * 8);
      int rb = wc + i * 16 + l15;
      bf[i] = *(const f16x8*)(Bs + rb * 32 + (quad ^ ((rb >> 1) & 3)) * 8);
    }
#pragma unroll
    for (int i = 0; i < 4; ++i)
#pragma unroll
      for (int j = 0; j < 4; ++j)
        acc[i][j] = __builtin_amdgcn_mfma_f32_16x16x32_f16(af[i], bf[j], acc[i][j], 0, 0, 0);
  }
#pragma unroll
  for (int j = 0; j < 4; ++j) {
    int col = bn + wc + j * 16 + l15;
    float bb = bias[col];
#pragma unroll
    for (int i = 0; i < 4; ++i) {
      int rowb = bm + wr + i * 16 + quad * 4;
#pragma unroll
      for (int r = 0; r < 4; ++r)
        out[(size_t)(rowb + r) * 512 + col] = acc[i][j][r] + bb;
    }
  }
}

extern "C" void kernel_launch(void* const* d_in, const int* in_sizes, int n_in,
                              void* d_out, int out_size, void* d_ws, size_t ws_size,
                              hipStream_t stream) {
  const float* x  = (const float*)d_in[0];
  const float* Wq = (const float*)d_in[1];
  const float* bq = (const float*)d_in[2];
  const float* Wk = (const float*)d_in[3];
  const float* bk = (const float*)d_in[4];
  const float* Wv = (const float*)d_in[5];
  const float* bv = (const float*)d_in[6];
  const float* Wo = (const float*)d_in[7];
  const float* bo = (const float*)d_in[8];
  float* out = (float*)d_out;
  char* ws = (char*)d_ws;

  _Float16* xs16   = (_Float16*)(ws);                          // 8 MB (reused as O16)
  _Float16* QK     = (_Float16*)(ws + (8u << 20));             // 16 MB
  _Float16* Vt     = (_Float16*)(ws + (24u << 20));            // 8 MB
  _Float16* Wqkv16 = (_Float16*)(ws + (32u << 20));            // 1.5 MB
  _Float16* Wo16   = (_Float16*)(ws + (32u << 20) + 1572864);  // 0.5 MB
  float*    bqkv   = (float*)   (ws + (32u << 20) + 2097152);  // 6 KB

  hipLaunchKernelGGL(prep_x, dim3(32, 16, 8), dim3(32, 8), 0, stream, x, xs16);
  hipLaunchKernelGGL(prep_w, dim3(1024), dim3(256), 0, stream,
                     Wq, bq, Wk, bk, Wv, bv, Wo, Wqkv16, bqkv, Wo16);
  hipLaunchKernelGGL(qkv_gemm, dim3(64, 12), dim3(256), 0, stream,
                     xs16, Wqkv16, bqkv, QK, Vt);
  hipLaunchKernelGGL(attn, dim3(8, 64), dim3(128), 0, stream, QK, Vt, xs16);
  hipLaunchKernelGGL(out_gemm, dim3(64, 4), dim3(256), 0, stream,
                     xs16, Wo16, bo, out);
}

// Round 3
// 144.565 us; speedup vs baseline: 1.1766x; 1.1114x over previous
//
#include <hip/hip_runtime.h>

// MultiHeadSelfAttention: N=8, C=512, heads=8, d=64, S=1024 (32x32), fp32 in/out.
// R3: (a) qkv epilogue V-transpose via LDS -> coalesced 16B Vt stores (kills the
// 2B/2KB-stride scatter, ~16x write amplification); (b) prep_x+prep_w merged;
// (c) attn at 256 thr/block (32 q-rows/wave) for 2 waves/SIMD TLP.

typedef _Float16 f16x8 __attribute__((ext_vector_type(8)));
typedef _Float16 f16x4 __attribute__((ext_vector_type(4)));
typedef float f32x4 __attribute__((ext_vector_type(4)));

__device__ inline void gl_lds16(const void* g, void* l) {
  __builtin_amdgcn_global_load_lds((const __attribute__((address_space(1))) void*)g,
                                   (__attribute__((address_space(3))) void*)l, 16, 0, 0);
}

__device__ inline float fexp2(float x) {
#if __has_builtin(__builtin_amdgcn_exp2f)
  return __builtin_amdgcn_exp2f(x);
#else
  return exp2f(x);
#endif
}

// ---------------- prep: x transpose+cast AND weight cast, one kernel ----------
__global__ void prep(const float* __restrict__ x,
                     const float* __restrict__ Wq, const float* __restrict__ bq,
                     const float* __restrict__ Wk, const float* __restrict__ bk,
                     const float* __restrict__ Wv, const float* __restrict__ bv,
                     const float* __restrict__ Wo,
                     _Float16* __restrict__ xs16, _Float16* __restrict__ Wqkv16,
                     float* __restrict__ bqkv, _Float16* __restrict__ Wo16) {
  __shared__ float t[32][33];
  const int tid = threadIdx.x;
  if (blockIdx.x < 1024) {
    const float g = 0.18033688011112042f;  // log2(e)/8
    int i = blockIdx.x * 256 + tid;
    Wqkv16[i]          = (_Float16)(Wq[i] * g);
    Wqkv16[262144 + i] = (_Float16)Wk[i];
    Wqkv16[524288 + i] = (_Float16)Wv[i];
    Wo16[i]            = (_Float16)Wo[i];
    if (i < 512) {
      bqkv[i]        = bq[i] * g;
      bqkv[512 + i]  = bk[i];
      bqkv[1024 + i] = bv[i];
    }
    return;
  }
  const int bid = blockIdx.x - 1024;            // 0..4095
  const int n = bid >> 9, c0 = ((bid >> 5) & 15) * 32, s0 = (bid & 31) * 32;
  const int tx = tid & 31, ty = tid >> 5;       // ty 0..7
#pragma unroll
  for (int i = 0; i < 4; ++i) {
    int cc = ty + i * 8;
    t[cc][tx] = x[((size_t)n * 512 + c0 + cc) * 1024 + s0 + tx];
  }
  __syncthreads();
#pragma unroll
  for (int i = 0; i < 4; ++i) {
    int ss = ty + i * 8;
    xs16[((size_t)n * 1024 + s0 + ss) * 512 + c0 + tx] = (_Float16)t[tx][ss];
  }
}

// ---------------- QKV GEMM: (8192x512)*(1536x512)^T + bias -------------------
// Q,K -> QK[m][0..1023] fp16 ; V -> Vt[(n*8+h)][d][p] fp16, s-permuted so that
// within each 32-block, position p = q*8 + t*4 + r holds s_local = 16t + 4q + r.
// V tiles transpose through LDS -> coalesced 16B global stores.
__global__ __launch_bounds__(256, 2) void qkv_gemm(
    const _Float16* __restrict__ A, const _Float16* __restrict__ Bw,
    const float* __restrict__ bias, _Float16* __restrict__ QK,
    _Float16* __restrict__ Vt) {
  __shared__ _Float16 smem[16896];  // As[0:4096) Bs[4096:8192); epilogue T 128x132
  _Float16* As = smem;
  _Float16* Bs = smem + 4096;
  const int tid = threadIdx.x;
  const int lane = tid & 63, w = tid >> 6;
  const int quad = lane >> 4, l15 = lane & 15;
  const int bm = blockIdx.x * 128, bn = blockIdx.y * 128;
  const int wr = (w >> 1) * 64, wc = (w & 1) * 64;
  f32x4 acc[4][4] = {};
  for (int k0 = 0; k0 < 512; k0 += 32) {
    __syncthreads();
#pragma unroll
    for (int c = 0; c < 2; ++c) {
      int idx = c * 256 + tid;
      int row = idx >> 2, sc = idx & 3;
      int kg = sc ^ ((row >> 1) & 3);
      gl_lds16(A + (size_t)(bm + row) * 512 + k0 + kg * 8, As + idx * 8);
      gl_lds16(Bw + (size_t)(bn + row) * 512 + k0 + kg * 8, Bs + idx * 8);
    }
    __syncthreads();
    f16x8 af[4], bf[4];
#pragma unroll
    for (int i = 0; i < 4; ++i) {
      int ra = wr + i * 16 + l15;
      af[i] = *(const f16x8*)(As + ra * 32 + (quad ^ ((ra >> 1) & 3)) * 8);
      int rb = wc + i * 16 + l15;
      bf[i] = *(const f16x8*)(Bs + rb * 32 + (quad ^ ((rb >> 1) & 3)) * 8);
    }
#pragma unroll
    for (int i = 0; i < 4; ++i)
#pragma unroll
      for (int j = 0; j < 4; ++j)
        acc[i][j] = __builtin_amdgcn_mfma_f32_16x16x32_f16(af[i], bf[j], acc[i][j], 0, 0, 0);
  }
  if (blockIdx.y < 8) {
    // Q/K blocks: direct store (lanes contiguous in col -> coalesced)
#pragma unroll
    for (int j = 0; j < 4; ++j) {
      int col = bn + wc + j * 16 + l15;
      float bb = bias[col];
#pragma unroll
      for (int i = 0; i < 4; ++i) {
        int rowb = bm + wr + i * 16 + quad * 4;
#pragma unroll
        for (int r = 0; r < 4; ++r)
          QK[(size_t)(rowb + r) * 1024 + col] = (_Float16)(acc[i][j][r] + bb);
      }
    }
  } else {
    // V blocks: transpose tile through LDS, store coalesced with s-permutation
    __syncthreads();  // As/Bs dead; reuse smem as T[col][row], stride 132
#pragma unroll
    for (int j = 0; j < 4; ++j) {
      int cl = wc + j * 16 + l15;
      float bb = bias[bn + cl];
#pragma unroll
      for (int i = 0; i < 4; ++i) {
        int row = wr + i * 16 + quad * 4;
        f16x4 pk;
#pragma unroll
        for (int r = 0; r < 4; ++r) pk[r] = (_Float16)(acc[i][j][r] + bb);
        *(f16x4*)(smem + cl * 132 + row) = pk;
      }
    }
    __syncthreads();
    const int n = bm >> 10, s0g = bm & 1023;
    const int vh = (bn - 1024) >> 6;
    const int cl = tid >> 1, par = tid & 1;
    const int hh = vh + (cl >> 6), d = cl & 63;
    const size_t vrow = (((size_t)((n * 8 + hh) * 64 + d)) << 10) + s0g;
#pragma unroll
    for (int g = 0; g < 8; ++g) {
      int pb = g * 16 + par * 8;
      int a32 = pb & ~31, q = (pb >> 3) & 3;
      f16x4 lo = *(const f16x4*)(smem + cl * 132 + a32 + 4 * q);
      f16x4 hi = *(const f16x4*)(smem + cl * 132 + a32 + 16 + 4 * q);
      f16x8 o = {lo[0], lo[1], lo[2], lo[3], hi[0], hi[1], hi[2], hi[3]};
      *(f16x8*)(Vt + vrow + pb) = o;
    }
  }
}

// ---------------- flash attention v3 ------------------------------------------
// 256 threads (4 waves), 128 q-rows/block (32 per wave) -> 2 waves/SIMD at
// 2 blocks/CU. Grid: (8 q-tiles, 64 n*h). LDS 48 KB.
__global__ __launch_bounds__(256, 2) void attn(
    const _Float16* __restrict__ QK, const _Float16* __restrict__ Vt,
    _Float16* __restrict__ O16) {
  __shared__ _Float16 Qs[128 * 64];
  __shared__ _Float16 Ks[128 * 64];
  __shared__ _Float16 Vs[64 * 128];
  const int tid = threadIdx.x, lane = tid & 63, w = tid >> 6;
  const int quad = lane >> 4, l15 = lane & 15;
  const int n = blockIdx.y >> 3, h = blockIdx.y & 7;
  const int q0 = blockIdx.x * 128;
#pragma unroll
  for (int c = 0; c < 4; ++c) {
    int idx = c * 256 + tid;
    int row = idx >> 3, sc = idx & 7;
    int dg = sc ^ (row & 7);
    gl_lds16(QK + (size_t)(n * 1024 + q0 + row) * 1024 + h * 64 + dg * 8, Qs + idx * 8);
  }
  __syncthreads();
  f16x8 qf[2][2];
#pragma unroll
  for (int mt = 0; mt < 2; ++mt)
#pragma unroll
    for (int dc = 0; dc < 2; ++dc) {
      int row = w * 32 + mt * 16 + l15;
      qf[mt][dc] = *(const f16x8*)(Qs + row * 64 + ((dc * 4 + quad) ^ (row & 7)) * 8);
    }
  f32x4 oacc[2][4] = {};
  f32x4 lsum[2] = {};
  const f16x8 ones = {(_Float16)1, (_Float16)1, (_Float16)1, (_Float16)1,
                      (_Float16)1, (_Float16)1, (_Float16)1, (_Float16)1};

  for (int kt = 0; kt < 8; ++kt) {
    __syncthreads();
#pragma unroll
    for (int c = 0; c < 4; ++c) {
      int idx = c * 256 + tid;
      int row = idx >> 3, sck = idx & 7;
      int dg = sck ^ (row & 7);
      gl_lds16(QK + (size_t)(n * 1024 + kt * 128 + row) * 1024 + 512 + h * 64 + dg * 8,
               Ks + idx * 8);
      int d = idx >> 4, scv = idx & 15;
      int vg = scv ^ (d & 7);
      gl_lds16(Vt + (size_t)((n * 8 + h) * 64 + d) * 1024 + kt * 128 + vg * 8,
               Vs + idx * 8);
    }
    __syncthreads();
#pragma unroll
    for (int sc = 0; sc < 4; ++sc) {
      f32x4 sacc[2][2] = {};
#pragma unroll
      for (int t = 0; t < 2; ++t) {
        int rk = (sc * 2 + t) * 16 + l15;
        f16x8 kf0 = *(const f16x8*)(Ks + rk * 64 + ((quad) ^ (rk & 7)) * 8);
        f16x8 kf1 = *(const f16x8*)(Ks + rk * 64 + ((4 + quad) ^ (rk & 7)) * 8);
#pragma unroll
        for (int mt = 0; mt < 2; ++mt) {
          sacc[mt][t] = __builtin_amdgcn_mfma_f32_16x16x32_f16(kf0, qf[mt][0], sacc[mt][t], 0, 0, 0);
          sacc[mt][t] = __builtin_amdgcn_mfma_f32_16x16x32_f16(kf1, qf[mt][1], sacc[mt][t], 0, 0, 0);
        }
      }
      f16x8 pf[2];
#pragma unroll
      for (int mt = 0; mt < 2; ++mt) {
#pragma unroll
        for (int t = 0; t < 2; ++t)
#pragma unroll
          for (int r = 0; r < 4; ++r)
            pf[mt][t * 4 + r] = (_Float16)fexp2(sacc[mt][t][r]);
        lsum[mt] = __builtin_amdgcn_mfma_f32_16x16x32_f16(pf[mt], ones, lsum[mt], 0, 0, 0);
      }
#pragma unroll
      for (int nt = 0; nt < 4; ++nt) {
        int rd = nt * 16 + l15;
        f16x8 vf = *(const f16x8*)(Vs + rd * 128 + ((sc * 4 + quad) ^ (rd & 7)) * 8);
#pragma unroll
        for (int mt = 0; mt < 2; ++mt)
          oacc[mt][nt] = __builtin_amdgcn_mfma_f32_16x16x32_f16(pf[mt], vf, oacc[mt][nt], 0, 0, 0);
      }
    }
  }
  // store with torch-reshape permutation: (n,h,s,d) -> i = h*128+s/8, j=(s%8)*64+d
#pragma unroll
  for (int mt = 0; mt < 2; ++mt) {
#pragma unroll
    for (int r = 0; r < 4; ++r) {
      float rinv = 1.0f / lsum[mt][r];
      int s = q0 + w * 32 + mt * 16 + quad * 4 + r;
      int i = h * 128 + (s >> 3);
      int jb = (s & 7) * 64;
#pragma unroll
      for (int nt = 0; nt < 4; ++nt) {
        int d = nt * 16 + l15;
        O16[(size_t)(n * 1024 + i) * 512 + jb + d] = (_Float16)(oacc[mt][nt][r] * rinv);
      }
    }
  }
}

// ---------------- out GEMM: (8192x512)*(512x512)^T + bo -> fp32 out ----------
__global__ __launch_bounds__(256, 2) void out_gemm(
    const _Float16* __restrict__ A, const _Float16* __restrict__ Bw,
    const float* __restrict__ bias, float* __restrict__ out) {
  __shared__ _Float16 As[128 * 32];
  __shared__ _Float16 Bs[128 * 32];
  const int tid = threadIdx.x;
  const int lane = tid & 63, w = tid >> 6;
  const int quad = lane >> 4, l15 = lane & 15;
  const int bm = blockIdx.x * 128, bn = blockIdx.y * 128;
  const int wr = (w >> 1) * 64, wc = (w & 1) * 64;
  f32x4 acc[4][4] = {};
  for (int k0 = 0; k0 < 512; k0 += 32) {
    __syncthreads();
#pragma unroll
    for (int c = 0; c < 2; ++c) {
      int idx = c * 256 + tid;
      int row = idx >> 2, sc = idx & 3;
      int kg = sc ^ ((row >> 1) & 3);
      gl_lds16(A + (size_t)(bm + row) * 512 + k0 + kg * 8, As + idx * 8);
      gl_lds16(Bw + (size_t)(bn + row) * 512 + k0 + kg * 8, Bs + idx * 8);
    }
    __syncthreads();
    f16x8 af[4], bf[4];
#pragma unroll
    for (int i = 0; i < 4; ++i) {
      int ra = wr + i * 16 + l15;
      af[i] = *(const f16x8*)(As + ra * 32 + (quad ^ ((ra >> 1) & 3)) * 8);
      int rb = wc + i * 16 + l15;
      bf[i] = *(const f16x8*)(Bs + rb * 32 + (quad ^ ((rb >> 1) & 3)) * 8);
    }
#pragma unroll
    for (int i = 0; i < 4; ++i)
#pragma unroll
      for (int j = 0; j < 4; ++j)
        acc[i][j] = __builtin_amdgcn_mfma_f32_16x16x32_f16(af[i], bf[j], acc[i][j], 0, 0, 0);
  }
#pragma unroll
  for (int j = 0; j < 4; ++j) {
    int col = bn + wc + j * 16 + l15;
    float bb = bias[col];
#pragma unroll
    for (int i = 0; i < 4; ++i) {
      int rowb = bm + wr + i * 16 + quad * 4;
#pragma unroll
      for (int r = 0; r < 4; ++r)
        out[(size_t)(rowb + r) * 512 + col] = acc[i][j][r] + bb;
    }
  }
}

extern "C" void kernel_launch(void* const* d_in, const int* in_sizes, int n_in,
                              void* d_out, int out_size, void* d_ws, size_t ws_size,
                              hipStream_t stream) {
  const float* x  = (const float*)d_in[0];
  const float* Wq = (const float*)d_in[1];
  const float* bq = (const float*)d_in[2];
  const float* Wk = (const float*)d_in[3];
  const float* bk = (const float*)d_in[4];
  const float* Wv = (const float*)d_in[5];
  const float* bv = (const float*)d_in[6];
  const float* Wo = (const float*)d_in[7];
  const float* bo = (const float*)d_in[8];
  float* out = (float*)d_out;
  char* ws = (char*)d_ws;

  _Float16* xs16   = (_Float16*)(ws);                          // 8 MB (reused as O16)
  _Float16* QK     = (_Float16*)(ws + (8u << 20));             // 16 MB
  _Float16* Vt     = (_Float16*)(ws + (24u << 20));            // 8 MB
  _Float16* Wqkv16 = (_Float16*)(ws + (32u << 20));            // 1.5 MB
  _Float16* Wo16   = (_Float16*)(ws + (32u << 20) + 1572864);  // 0.5 MB
  float*    bqkv   = (float*)   (ws + (32u << 20) + 2097152);  // 6 KB

  hipLaunchKernelGGL(prep, dim3(5120), dim3(256), 0, stream,
                     x, Wq, bq, Wk, bk, Wv, bv, Wo, xs16, Wqkv16, bqkv, Wo16);
  hipLaunchKernelGGL(qkv_gemm, dim3(64, 12), dim3(256), 0, stream,
                     xs16, Wqkv16, bqkv, QK, Vt);
  hipLaunchKernelGGL(attn, dim3(8, 64), dim3(256), 0, stream, QK, Vt, xs16);
  hipLaunchKernelGGL(out_gemm, dim3(64, 4), dim3(256), 0, stream,
                     xs16, Wo16, bo, out);
}